// Round 5
// baseline (1969.493 us; speedup 1.0000x reference)
//
#include <hip/hip_runtime.h>

typedef _Float16 h2  __attribute__((ext_vector_type(2)));
typedef _Float16 h8  __attribute__((ext_vector_type(8)));
typedef float    f4  __attribute__((ext_vector_type(4)));
typedef short    s8  __attribute__((ext_vector_type(8)));

#define NTOK 65536              // B*L = 32*2048
#define L_ 2048

// workspace layout (bytes), total exactly 192 MiB (validated in rounds 3/4):
//   xp_rz : NTOK*768  f16   [tok][dir][j][{r,z}]
//   xp_n  : NTOK*384  f16   [tok][dir][j]
//   allh  : NTOK*384  bf16  [b][pos][dir*192+j]
#define XP_RZ_BYTES ((size_t)NTOK * 768 * 2)
#define XP_N_BYTES  ((size_t)NTOK * 384 * 2)

__device__ __forceinline__ unsigned short f2bf(float f){
    union { float f; unsigned int i; } v; v.f = f;
    unsigned int r = v.i + 0x7FFFu + ((v.i >> 16) & 1u);   // RNE, finite inputs
    return (unsigned short)(r >> 16);
}
__device__ __forceinline__ float bf2f(unsigned short u){
    union { unsigned int i; float f; } v; v.i = ((unsigned)u) << 16; return v.f;
}
__device__ __forceinline__ void load8_f32_bf16(void* dst, const float* p){
    f4 a = *(const f4*)p;
    f4 b = *(const f4*)(p + 4);
    unsigned short o[8] = {f2bf(a[0]),f2bf(a[1]),f2bf(a[2]),f2bf(a[3]),
                           f2bf(b[0]),f2bf(b[1]),f2bf(b[2]),f2bf(b[3])};
    *(uint4*)dst = *(const uint4*)o;
}
__device__ __forceinline__ float quad_allreduce(float v){
    int x = __builtin_amdgcn_update_dpp(0, __float_as_int(v), 0xB1, 0xF, 0xF, true); // quad_perm(1,0,3,2)
    v += __int_as_float(x);
    x = __builtin_amdgcn_update_dpp(0, __float_as_int(v), 0x4E, 0xF, 0xF, true);     // quad_perm(2,3,0,1)
    v += __int_as_float(x);
    return v;
}
// async global->LDS DMA, 16B per lane; LDS dst = wave-uniform base + lane*16
__device__ __forceinline__ void gload_lds16(const _Float16* g, _Float16* l){
    __builtin_amdgcn_global_load_lds(
        (const __attribute__((address_space(1))) unsigned int*)(const void*)g,
        (__attribute__((address_space(3))) unsigned int*)(void*)l, 16, 0, 0);
}

// ---------------- Kernel 1: embedding gather + dual-direction input projection ----------------
__global__ __launch_bounds__(256) void k_proj(
    const int* __restrict__ ids,
    const float* __restrict__ emb,
    const float* __restrict__ wf,
    const float* __restrict__ wb,
    const float* __restrict__ bf_,
    const float* __restrict__ bb_,
    _Float16* __restrict__ xp_rz,
    _Float16* __restrict__ xp_n)
{
    __shared__ __align__(16) unsigned short As[128][72];   // 64 K + 8 pad
    __shared__ __align__(16) unsigned short Bs[128][72];
    const int mBase = blockIdx.x * 128;
    const int nBase = blockIdx.y * 128;      // over 1152 = [f:576 | b:576], each gate*192+j
    const int tid = threadIdx.x;
    const int w = tid >> 6, lane = tid & 63;
    const int quad = lane >> 4, col = lane & 15;
    f4 acc[2][8] = {};
    for (int k0 = 0; k0 < 256; k0 += 64){
        __syncthreads();
        #pragma unroll
        for (int i = 0; i < 4; ++i){
            int cc = tid + i*256;
            int row = cc >> 3, c8 = cc & 7;
            int id = ids[mBase + row];
            id = (id < 0) ? 0 : ((id > 1000) ? 1000 : id);
            load8_f32_bf16(&As[row][c8*8], emb + (long)id*256 + k0 + c8*8);
        }
        #pragma unroll
        for (int i = 0; i < 4; ++i){
            int cc = tid + i*256;
            int row = cc >> 3, c8 = cc & 7;
            int g = nBase + row;
            const float* src = (g < 576) ? (wf + (long)g*256) : (wb + (long)(g-576)*256);
            load8_f32_bf16(&Bs[row][c8*8], src + k0 + c8*8);
        }
        __syncthreads();
        #pragma unroll
        for (int s = 0; s < 2; ++s){
            int ko = s*32 + quad*8;
            s8 a0 = *(const s8*)(&As[(w<<5) + col][ko]);
            s8 a1 = *(const s8*)(&As[(w<<5) + 16 + col][ko]);
            #pragma unroll
            for (int nt = 0; nt < 8; ++nt){
                s8 bv = *(const s8*)(&Bs[nt*16 + col][ko]);
                acc[0][nt] = __builtin_amdgcn_mfma_f32_16x16x32_bf16(a0, bv, acc[0][nt], 0,0,0);
                acc[1][nt] = __builtin_amdgcn_mfma_f32_16x16x32_bf16(a1, bv, acc[1][nt], 0,0,0);
            }
        }
    }
    // D layout: col = lane&15 (N), row = quad*4 + reg (M)  [m89-verified]
    #pragma unroll
    for (int nt = 0; nt < 8; ++nt){
        int g = nBase + nt*16 + col;
        int dir = (g >= 576) ? 1 : 0;
        int rr = g - dir*576;
        int gate = rr / 192;
        int j = rr - gate*192;
        float bias = dir ? bb_[rr] : bf_[rr];
        #pragma unroll
        for (int mt = 0; mt < 2; ++mt){
            #pragma unroll
            for (int r = 0; r < 4; ++r){
                int m = mBase + (w<<5) + mt*16 + quad*4 + r;
                float v = acc[mt][nt][r] + bias;
                if (gate < 2) xp_rz[(size_t)m*768 + dir*384 + j*2 + gate] = (_Float16)v;
                else          xp_n [(size_t)m*384 + dir*192 + j]          = (_Float16)v;
            }
        }
    }
}

// ---------------- Kernel 2: GRU scan, one block per (batch, direction) ----------------
// 768 threads = 192 units x 4 lanes; lane c covers k in [48c, 48c+48).
// xp staged through LDS in 32-step chunks via async global_load_lds DMA:
// per chunk each wave issues 3 x 16B-DMA; the ONLY vmcnt wait is one
// vmcnt(0) per 32 steps at the chunk boundary (loads are ~19k cyc old then).
__global__ __launch_bounds__(768, 3) void k_scan(
    const float* __restrict__ whh_f,
    const float* __restrict__ bhh_f,
    const float* __restrict__ whh_b,
    const float* __restrict__ bhh_b,
    const _Float16* __restrict__ xp_rz,
    const _Float16* __restrict__ xp_n,
    unsigned short* __restrict__ allh)
{
    __shared__ __align__(16) _Float16 rzbuf[2][32][384];   // 48 KB
    __shared__ __align__(16) _Float16 nbuf [2][32][192];   // 24 KB
    __shared__ __align__(16) _Float16 hbuf [2][192];
    const int bd = blockIdx.x;
    const int b = bd >> 1, dir = bd & 1;
    const int tid = threadIdx.x;
    const int j = tid >> 2, c = tid & 3;
    const int wv = tid >> 6, lane = tid & 63;
    const float* whh = dir ? whh_b : whh_f;
    const float* bhh = dir ? bhh_b : bhh_f;

    // W_hh in VGPRs as f16 (2^-11 rel err from f32)
    h2 wr[24], wz[24], wn[24];
    {
        const float* r0 = whh + (long)(0*192 + j)*192 + c*48;
        const float* r1 = whh + (long)(1*192 + j)*192 + c*48;
        const float* r2 = whh + (long)(2*192 + j)*192 + c*48;
        #pragma unroll
        for (int kk = 0; kk < 24; ++kk){
            wr[kk] = h2{(_Float16)r0[2*kk], (_Float16)r0[2*kk+1]};
            wz[kk] = h2{(_Float16)r1[2*kk], (_Float16)r1[2*kk+1]};
            wn[kk] = h2{(_Float16)r2[2*kk], (_Float16)r2[2*kk+1]};
        }
    }
    const float bhr = bhh[j];
    const float bhz = bhh[192 + j];
    const float bhn = bhh[384 + j];

    if (tid < 192) hbuf[0][tid] = (_Float16)0.f;

    // ---- chunk DMA issue: 24 rz wave-chunks + 12 n wave-chunks = 12 waves x 3 ----
    auto issue_chunk = [&](int baseT, int buf){
        #pragma unroll
        for (int i = 0; i < 3; ++i){
            int q = wv*3 + i;                      // wave-uniform
            if (q < 24){
                int s = q*64 + lane;               // 0..1535
                int row = s / 48, col = s - row*48;
                int tt = baseT + row;
                int p = dir ? (2047 - tt) : tt;
                const _Float16* g = xp_rz + (size_t)(b*2048 + p)*768 + dir*384 + col*8;
                gload_lds16(g, &rzbuf[buf][0][0] + q*512);
            } else {
                int qn = q - 24;
                int s = qn*64 + lane;              // 0..767
                int row = s / 24, col = s - row*24;
                int tt = baseT + row;
                int p = dir ? (2047 - tt) : tt;
                const _Float16* g = xp_n + (size_t)(b*2048 + p)*384 + dir*192 + col*8;
                gload_lds16(g, &nbuf[buf][0][0] + qn*512);
            }
        }
    };

    issue_chunk(0, 0);
    __syncthreads();   // vmcnt(0)+lgkmcnt(0)+barrier: chunk 0 visible, hbuf init visible

    unsigned short* hout = allh + (size_t)b*L_*384 + dir*192 + j;
    float hprev = 0.f;

    for (int ch = 0; ch < 64; ++ch){
        if (ch < 63) issue_chunk((ch+1)*32, (ch+1)&1);
        const _Float16 (*rz)[384] = rzbuf[ch&1];
        const _Float16 (*nn)[192] = nbuf[ch&1];
        for (int r = 0; r < 32; ++r){
            const int t = ch*32 + r;
            const int cur = r & 1, nxt = cur ^ 1;   // t&1 == r&1 (32 even)

            float ar0=0.f, ar1=0.f, ar2=0.f;
            float az0=0.f, az1=0.f, az2=0.f;
            float an0=0.f, an1=0.f, an2=0.f;
            const h8* hp = (const h8*)(&hbuf[cur][c*48]);
            #pragma unroll
            for (int i = 0; i < 6; ++i){
                h8 hv = hp[i];
                #pragma unroll
                for (int q = 0; q < 4; ++q){
                    h2 hx = h2{hv[2*q], hv[2*q+1]};
                    int kk = i*4 + q;
                    if (i % 3 == 0){
                        ar0 = __builtin_amdgcn_fdot2(wr[kk], hx, ar0, false);
                        az0 = __builtin_amdgcn_fdot2(wz[kk], hx, az0, false);
                        an0 = __builtin_amdgcn_fdot2(wn[kk], hx, an0, false);
                    } else if (i % 3 == 1){
                        ar1 = __builtin_amdgcn_fdot2(wr[kk], hx, ar1, false);
                        az1 = __builtin_amdgcn_fdot2(wz[kk], hx, az1, false);
                        an1 = __builtin_amdgcn_fdot2(wn[kk], hx, an1, false);
                    } else {
                        ar2 = __builtin_amdgcn_fdot2(wr[kk], hx, ar2, false);
                        az2 = __builtin_amdgcn_fdot2(wz[kk], hx, az2, false);
                        an2 = __builtin_amdgcn_fdot2(wn[kk], hx, an2, false);
                    }
                }
            }
            float ar = quad_allreduce((ar0 + ar1) + ar2);
            float az = quad_allreduce((az0 + az1) + az2);
            float an = quad_allreduce((an0 + an1) + an2);

            // gate math on ALL lanes (allreduce already broadcast the sums;
            // redundant-but-uniform beats a divergent branch)
            h2 xv = *(const h2*)(&rz[r][j*2]);
            float xr = (float)xv[0], xz = (float)xv[1];
            float xn = (float)nn[r][j];
            float rg = __builtin_amdgcn_rcpf(1.f + __expf(-(xr + ar + bhr)));
            float zg = __builtin_amdgcn_rcpf(1.f + __expf(-(xz + az + bhz)));
            float narg = fmaf(rg, an + bhn, xn);
            float nv = fmaf(2.f, __builtin_amdgcn_rcpf(1.f + __expf(-2.f*narg)), -1.f);
            float h = fmaf(zg, hprev - nv, nv);
            hprev = h;
            if (c == 0){
                hbuf[nxt][j] = (_Float16)h;
                int pos = dir ? (L_-1 - t) : t;
                hout[(size_t)pos*384] = f2bf(h);   // fire-and-forget
            }
            if (r < 31){
                // steady-state barrier: LDS visibility only, no vmcnt drain
                __asm__ __volatile__("s_waitcnt lgkmcnt(0)\n\ts_barrier" ::: "memory");
            }
        }
        // chunk boundary: wait own DMA (issued 32 steps ago -> ~free) + LDS, then barrier
        __asm__ __volatile__("s_waitcnt vmcnt(0) lgkmcnt(0)\n\ts_barrier" ::: "memory");
    }
}

// ---------------- Kernel 3: start/end gather, f32 output ----------------
__global__ __launch_bounds__(256) void k_gather(
    const int* __restrict__ start_ids,
    const int* __restrict__ end_ids,
    const unsigned short* __restrict__ allh,
    float* __restrict__ out)
{
    int t = blockIdx.x * 256 + threadIdx.x;       // 1,572,864 threads, 8 elems each
    int k8 = t % 96;
    int rest = t / 96;
    int s = rest & 511;
    int b = rest >> 9;
    int k = k8 * 8;
    int off, pos;
    if (k < 384){ off = k;       pos = start_ids[b*512 + s]; }
    else        { off = k - 384; pos = end_ids  [b*512 + s]; }
    pos = (pos < 0) ? 0 : ((pos > 2047) ? 2047 : pos);
    const unsigned short* src = allh + (size_t)(b*2048 + pos)*384 + off;
    uint4 v = *(const uint4*)src;
    const unsigned short* h = (const unsigned short*)&v;
    float* outf = out + (size_t)t*8;
    f4 lo = {bf2f(h[0]), bf2f(h[1]), bf2f(h[2]), bf2f(h[3])};
    f4 hi = {bf2f(h[4]), bf2f(h[5]), bf2f(h[6]), bf2f(h[7])};
    *(f4*)outf = lo;
    *(f4*)(outf + 4) = hi;
}

extern "C" void kernel_launch(void* const* d_in, const int* in_sizes, int n_in,
                              void* d_out, int out_size, void* d_ws, size_t ws_size,
                              hipStream_t stream)
{
    const int* ids   = (const int*)d_in[0];
    const int* sids  = (const int*)d_in[1];
    const int* eids  = (const int*)d_in[2];
    const float* emb  = (const float*)d_in[3];
    const float* wihf = (const float*)d_in[4];
    const float* whhf = (const float*)d_in[5];
    const float* bihf = (const float*)d_in[6];
    const float* bhhf = (const float*)d_in[7];
    const float* wihb = (const float*)d_in[8];
    const float* whhb = (const float*)d_in[9];
    const float* bihb = (const float*)d_in[10];
    const float* bhhb = (const float*)d_in[11];

    _Float16* xp_rz = (_Float16*)d_ws;
    _Float16* xp_n  = (_Float16*)((char*)d_ws + XP_RZ_BYTES);
    unsigned short* allh = (unsigned short*)((char*)d_ws + XP_RZ_BYTES + XP_N_BYTES);

    dim3 g1(512, 9);   // 512 M-tiles x 9 N-tiles (1152/128)
    k_proj<<<g1, 256, 0, stream>>>(ids, emb, wihf, wihb, bihf, bihb, xp_rz, xp_n);
    k_scan<<<64, 768, 0, stream>>>(whhf, bhhf, whhb, bhhb, xp_rz, xp_n, allh);
    k_gather<<<6144, 256, 0, stream>>>(sids, eids, allh, (float*)d_out);
}